// Round 8
// baseline (697.870 us; speedup 1.0000x reference)
//
#include <hip/hip_runtime.h>
#include <hip/hip_bf16.h>

// ConvSTFT as GEMM: C[b][c][f] = sum_k x_pad[b][f*100+k] * W[c][k]
// B=32, T=480000, WIN=400, HOP=100, C_OUT=514, PAD=300, NF=4803.
//
// R10 == R9 resubmit (container-acquisition flake, no kernel verdict):
//   k1: x fp32 -> padded bf16 (d_ws)
//   k2: w fp32 -> bf16 packed in MFMA FRAGMENT ORDER wp2[nt][kc][cb][lane]
//       (479 KB, L2-resident), so B is read DIRECTLY from global per kc as one
//       coalesced 1024B global_load_dwordx4 per wave -- no w_s, no w staging.
//   k3: persistent blocks, x-seg-major: each block owns 2-3 x-segs; per x-seg
//       stage x once (26.6 KB LDS, gl_lds), then loop ALL 9 nt tiles with NO
//       barriers (x_s read-only; B from L2; stores never hit a vmcnt(0) drain).
//       xp HBM fetch: 31 MB total (was ~287 MB with nt-major order).
//       Barriers: 2 per x-seg (overwrite-protect + publish), not 2 per tile.

#define T_LEN   480000
#define NF      4803
#define C_OUT   514
#define HOP     100
#define WIN     400
#define BM      128
#define BN      64
#define WSTR    424                 // (fallback only) padded K stride
#define XPS     487040              // per-batch padded x length (elems)
#define XP_TOTAL (32 * XPS)         // 15,585,280 elems
#define MT_CNT  38
#define NT_CNT  9
#define NSEG    (MT_CNT * 32)       // 1,216 x-segs
#define XSEG    13312               // bf16 elems in x buffer (need 13,116)
#define NBLK    512                 // 2 blocks/CU
// wp2: [nt][kc][cb][lane] 16B chunks; cb = chan_in_tile/16 (0..3), kc 0..12
#define WP2_CH    (NT_CNT * 13 * 4 * 64)   // 29,952 chunks
#define WP2_ELEMS (WP2_CH * 8)             // 239,616 bf16
#define WP2_BYTE_OFF ((size_t)XP_TOTAL * 2)
#define WS_NEEDED (WP2_BYTE_OFF + (size_t)WP2_ELEMS * 2)

typedef __attribute__((ext_vector_type(8))) short short8;
typedef __attribute__((ext_vector_type(4))) float f32x4;

__device__ __forceinline__ unsigned short f2bf(float f) {
    unsigned int u = __float_as_uint(f);
    u += 0x7FFFu + ((u >> 16) & 1u);   // RNE
    return (unsigned short)(u >> 16);
}

__device__ __forceinline__ void gl_lds16(const unsigned short* g, unsigned short* l) {
    __builtin_amdgcn_global_load_lds(
        (const __attribute__((address_space(1))) unsigned int*)(g),
        (__attribute__((address_space(3))) unsigned int*)(l), 16, 0, 0);
}

// ---------------- k1: x fp32 -> padded bf16 ----------------
__global__ void cvt_x_kernel(const float* __restrict__ x, unsigned short* __restrict__ xp) {
    const int t = blockIdx.x * 256 + threadIdx.x;     // one ushort4 per thread
    const int b  = t / (XPS / 4);
    const int i4 = t - b * (XPS / 4);
    const int i  = i4 * 4;
    const int g  = i - 300;
    ushort4 h;
    if (g >= 0 && g + 3 < T_LEN) {
        const float4 f = *(const float4*)(x + (size_t)b * T_LEN + g);
        h.x = f2bf(f.x); h.y = f2bf(f.y); h.z = f2bf(f.z); h.w = f2bf(f.w);
    } else {
        const float* xb = x + (size_t)b * T_LEN;
        h.x = (g + 0 >= 0 && g + 0 < T_LEN) ? f2bf(xb[g + 0]) : 0;
        h.y = (g + 1 >= 0 && g + 1 < T_LEN) ? f2bf(xb[g + 1]) : 0;
        h.z = (g + 2 >= 0 && g + 2 < T_LEN) ? f2bf(xb[g + 2]) : 0;
        h.w = (g + 3 >= 0 && g + 3 < T_LEN) ? f2bf(xb[g + 3]) : 0;
    }
    *(ushort4*)(xp + (size_t)b * XPS + i) = h;
}

// ---------------- k2: w -> bf16 fragment-order pack ----------------
// chunk t: lane = t&63; r=t>>6: cb = r&3; kc = (r>>2)%13; nt = (r>>2)/13
// element j of the chunk = W[chan][k], chan = nt*64 + cb*16 + (lane&15),
// k = kc*32 + (lane>>4)*8 + j. Zero outside [C_OUT, WIN].
__global__ void cvt_w2_kernel(const float* __restrict__ w, unsigned short* __restrict__ wp2) {
    const int t = blockIdx.x * 256 + threadIdx.x;
    if (t >= WP2_CH) return;
    const int lane = t & 63;
    int r = t >> 6;
    const int cb = r & 3; r >>= 2;
    const int kc = r % 13;
    const int nt = r / 13;
    const int chan = nt * 64 + cb * 16 + (lane & 15);
    const int k0   = kc * 32 + (lane >> 4) * 8;
    unsigned short h[8];
    #pragma unroll
    for (int j = 0; j < 8; ++j) {
        const int k = k0 + j;
        h[j] = (chan < C_OUT && k < WIN) ? f2bf(w[(size_t)chan * WIN + k]) : (unsigned short)0;
    }
    uint4 u;
    u.x = (unsigned)h[0] | ((unsigned)h[1] << 16);
    u.y = (unsigned)h[2] | ((unsigned)h[3] << 16);
    u.z = (unsigned)h[4] | ((unsigned)h[5] << 16);
    u.w = (unsigned)h[6] | ((unsigned)h[7] << 16);
    *(uint4*)(wp2 + (size_t)t * 8) = u;
}

// ---------------- k3: persistent GEMM, x-seg-major, barrier-free nt loop ----
__device__ __forceinline__ short8 ldB(const unsigned short* __restrict__ wp2,
                                      int nt, int kc, int cb, int lane) {
    return *(const short8*)(wp2 + (size_t)((((nt * 13 + kc) * 4 + cb) << 6) + lane) * 8);
}

__global__ __launch_bounds__(512, 4)   // 16 waves/CU: VGPR capped at 128
void stft_gemm(const unsigned short* __restrict__ xp,
               const unsigned short* __restrict__ wp2,
               float* __restrict__ out) {
    __shared__ unsigned short x_s[XSEG];          // 26,624 B only

    const int tid  = threadIdx.x;
    const int lane = tid & 63;
    const int wv   = tid >> 6;       // 0..7

    // 1216 x-segs over 512 blocks: blocks 0..191 own 3, rest own 2
    const int id   = blockIdx.x;
    const int s0   = (id < 192) ? id * 3 : 576 + (id - 192) * 2;
    const int nseg = (id < 192) ? 3 : 2;

    const int q4 = lane >> 4;
    const int lm = lane & 15;
    const int wr = wv & 3;           // M split: 4 waves x 32 frames
    const int wc = wv >> 2;          // N split: 2 waves x 32 chans

    // A: frame m = wr*32 + mi*16 + lm, k = q4*8 + j  -> x_s[frame*100 + k]
    int aoff[2];
    #pragma unroll
    for (int mi = 0; mi < 2; ++mi) aoff[mi] = (wr * 32 + mi * 16 + lm) * HOP + q4 * 8;

    for (int si = 0; si < nseg; ++si) {
        const int s  = s0 + si;
        const int b  = s / MT_CNT;
        const int mt = s - b * MT_CNT;

        // ---- stage x-seg (protect overwrite, then publish) ----
        __syncthreads();
        {
            const unsigned short* xg = xp + (size_t)b * XPS + mt * (BM * HOP);
            #pragma unroll
            for (int c = wv; c < 26; c += 8) {
                const int idx = (c << 6) + lane;
                gl_lds16(xg + idx * 8, x_s + idx * 8);
            }
        }
        __syncthreads();

        // ---- 9 nt tiles, NO barriers: x_s read-only, B from L2, stores fly ----
        for (int nt = 0; nt < NT_CNT; ++nt) {
            f32x4 acc[2][2];
            #pragma unroll
            for (int mi = 0; mi < 2; ++mi)
                #pragma unroll
                for (int ni = 0; ni < 2; ++ni)
                    acc[mi][ni] = (f32x4){0.f, 0.f, 0.f, 0.f};

            #pragma unroll
            for (int kc = 0; kc < 13; ++kc) {
                const int k = kc * 32;
                union { short8 v; unsigned long long u[2]; } au[2];
                #pragma unroll
                for (int mi = 0; mi < 2; ++mi) {
                    const unsigned long long* p = (const unsigned long long*)(x_s + aoff[mi] + k);
                    au[mi].u[0] = p[0]; au[mi].u[1] = p[1];
                }
                const short8 b0 = ldB(wp2, nt, kc, wc * 2 + 0, lane);
                const short8 b1 = ldB(wp2, nt, kc, wc * 2 + 1, lane);
                #pragma unroll
                for (int mi = 0; mi < 2; ++mi) {
                    acc[mi][0] = __builtin_amdgcn_mfma_f32_16x16x32_bf16(au[mi].v, b0, acc[mi][0], 0, 0, 0);
                    acc[mi][1] = __builtin_amdgcn_mfma_f32_16x16x32_bf16(au[mi].v, b1, acc[mi][1], 0, 0, 0);
                }
            }

            // ---- epilogue: plain stores (L2 merges 64B lines per 4-lane group) ----
            float* ob = out + (size_t)b * C_OUT * NF;
            const int f_base = mt * BM + wr * 32 + q4 * 4;
            const int c_base = nt * BN + wc * 32 + lm;
            #pragma unroll
            for (int mi = 0; mi < 2; ++mi) {
                const int fg = f_base + mi * 16;
                const bool fok = (fg + 3 < NF);
                #pragma unroll
                for (int ni = 0; ni < 2; ++ni) {
                    const int cg = c_base + ni * 16;
                    if (cg < C_OUT) {
                        float* op = ob + (size_t)cg * NF + fg;
                        if (fok) {
                            op[0] = acc[mi][ni][0]; op[1] = acc[mi][ni][1];
                            op[2] = acc[mi][ni][2]; op[3] = acc[mi][ni][3];
                        } else {
                            #pragma unroll
                            for (int rI = 0; rI < 4; ++rI)
                                if (fg + rI < NF) op[rI] = acc[mi][ni][rI];
                        }
                    }
                }
            }
        }
    }
}

// ---------------- fallback (R1 kernel) if ws too small ----------------
#define SEG 13120
__global__ __launch_bounds__(256, 2)
void conv_stft_fallback(const float* __restrict__ x,
                        const float* __restrict__ w,
                        float* __restrict__ out) {
    __shared__ short x_s[SEG];
    __shared__ short w_s[BN * WSTR];
    const int tid = threadIdx.x;
    const int nt  = blockIdx.x;
    const int mt  = blockIdx.y;
    const int b   = blockIdx.z;
    const int s0 = mt * (BM * HOP) - 300;
    const float* xb = x + (size_t)b * T_LEN;
    for (int v = tid; v < SEG / 4; v += 256) {
        int g = s0 + v * 4;
        float f0, f1, f2, f3;
        if (g >= 0 && g + 3 < T_LEN) {
            const float4 f = *(const float4*)(xb + g);
            f0 = f.x; f1 = f.y; f2 = f.z; f3 = f.w;
        } else {
            f0 = (g + 0 >= 0 && g + 0 < T_LEN) ? xb[g + 0] : 0.f;
            f1 = (g + 1 >= 0 && g + 1 < T_LEN) ? xb[g + 1] : 0.f;
            f2 = (g + 2 >= 0 && g + 2 < T_LEN) ? xb[g + 2] : 0.f;
            f3 = (g + 3 >= 0 && g + 3 < T_LEN) ? xb[g + 3] : 0.f;
        }
        ushort4 h; h.x = f2bf(f0); h.y = f2bf(f1); h.z = f2bf(f2); h.w = f2bf(f3);
        *(ushort4*)(&x_s[v * 4]) = h;
    }
    for (int s = tid; s < BN * 106; s += 256) {
        const int r  = s / 106;
        const int gk = s - r * 106;
        const int c  = nt * BN + r;
        ushort4 h = make_ushort4(0, 0, 0, 0);
        if (gk < 100 && c < C_OUT) {
            const float4 f = *(const float4*)(w + (size_t)c * WIN + gk * 4);
            h.x = f2bf(f.x); h.y = f2bf(f.y); h.z = f2bf(f.z); h.w = f2bf(f.w);
        }
        if (gk * 4 < WSTR) *(ushort4*)(&w_s[r * WSTR + gk * 4]) = h;
    }
    __syncthreads();
    const int lane = tid & 63, wv = tid >> 6, q = lane >> 4, lm = lane & 15;
    f32x4 acc[2][4];
    #pragma unroll
    for (int mi = 0; mi < 2; ++mi)
        #pragma unroll
        for (int ni = 0; ni < 4; ++ni) acc[mi][ni] = (f32x4){0.f,0.f,0.f,0.f};
    const int a0 = (wv * 32 + lm) * HOP + q * 8;
    const int a1 = a0 + 16 * HOP;
    int boff[4];
    #pragma unroll
    for (int ni = 0; ni < 4; ++ni) boff[ni] = (ni * 16 + lm) * WSTR + q * 8;
    #pragma unroll
    for (int kc = 0; kc < 13; ++kc) {
        const int k = kc * 32;
        union { short8 v; unsigned long long u[2]; } au0, au1;
        const unsigned long long* p0 = (const unsigned long long*)(x_s + a0 + k);
        const unsigned long long* p1 = (const unsigned long long*)(x_s + a1 + k);
        au0.u[0] = p0[0]; au0.u[1] = p0[1];
        au1.u[0] = p1[0]; au1.u[1] = p1[1];
        #pragma unroll
        for (int ni = 0; ni < 4; ++ni) {
            const short8 bf = *(const short8*)(&w_s[boff[ni] + k]);
            acc[0][ni] = __builtin_amdgcn_mfma_f32_16x16x32_bf16(au0.v, bf, acc[0][ni], 0, 0, 0);
            acc[1][ni] = __builtin_amdgcn_mfma_f32_16x16x32_bf16(au1.v, bf, acc[1][ni], 0, 0, 0);
        }
    }
    float* ob = out + (size_t)b * C_OUT * NF;
    const int f_base = mt * BM + wv * 32 + q * 4;
    const int c_base = nt * BN + lm;
    #pragma unroll
    for (int mi = 0; mi < 2; ++mi) {
        #pragma unroll
        for (int ni = 0; ni < 4; ++ni) {
            const int cg = c_base + ni * 16;
            if (cg < C_OUT) {
                float* op = ob + (size_t)cg * NF;
                #pragma unroll
                for (int r = 0; r < 4; ++r) {
                    const int fg = f_base + mi * 16 + r;
                    if (fg < NF) op[fg] = acc[mi][ni][r];
                }
            }
        }
    }
}

extern "C" void kernel_launch(void* const* d_in, const int* in_sizes, int n_in,
                              void* d_out, int out_size, void* d_ws, size_t ws_size,
                              hipStream_t stream) {
    const float* x = (const float*)d_in[0];   // [32, 480000] fp32
    const float* w = (const float*)d_in[1];   // [514, 1, 400] fp32
    float* out = (float*)d_out;               // [32, 514, 4803] fp32

    if (ws_size >= WS_NEEDED) {
        unsigned short* xp  = (unsigned short*)d_ws;
        unsigned short* wp2 = (unsigned short*)((char*)d_ws + WP2_BYTE_OFF);
        cvt_x_kernel<<<XP_TOTAL / 4 / 256, 256, 0, stream>>>(x, xp);
        cvt_w2_kernel<<<(WP2_CH + 255) / 256, 256, 0, stream>>>(w, wp2);
        stft_gemm<<<dim3(NBLK), 512, 0, stream>>>(xp, wp2, out);
    } else {
        dim3 grid(NT_CNT, MT_CNT, 32);
        conv_stft_fallback<<<grid, 256, 0, stream>>>(x, w, out);
    }
}